// Round 4
// baseline (128.033 us; speedup 1.0000x reference)
//
#include <hip/hip_runtime.h>
#include <cstdint>
#include <cstddef>

// Problem constants (match reference)
#define BATCH 16
#define NBLK 16
#define TB 256
#define EMBED 2048
#define NKV 8
#define GQ 4          // group size = NH / NKV = 32/8
#define HD 64
#define NQROWS 3072   // 2048 (q) + 512 (k_cur) + 512 (v_cur)
#define QSCALE 0.18033688011112042f  // 64^-0.5 * log2(e); scores in log2 domain

#define TILE_T 32     // tokens per LDS tile
#define NTILE 8       // 256 / 32

// Workspace layout (floats):
#define OFF_PARTMS 49152
#define OFF_PARTO  65536
#define OFF_ATTEN  589824

// global -> LDS async DMA, 16 B per lane (1 KB per instruction per wave).
// LDS dest must be the wave-uniform base; global src is per-lane.
#define GLDS16(gp, lp)                                          \
  __builtin_amdgcn_global_load_lds(                             \
      (const __attribute__((address_space(1))) uint32_t*)(gp),  \
      (__attribute__((address_space(3))) uint32_t*)(lp), 16, 0, 0)

__device__ __forceinline__ float dot4(float4 a, float4 b) {
  return a.x * b.x + a.y * b.y + a.z * b.z + a.w * b.w;
}

// DPP-based sum over each 16-lane group (pure VALU, no LDS pipe).
template <int CTRL>
__device__ __forceinline__ float dpp_add(float x) {
  return x + __int_as_float(
                 __builtin_amdgcn_mov_dpp(__float_as_int(x), CTRL, 0xF, 0xF, true));
}
__device__ __forceinline__ float red16(float x) {
  x = dpp_add<0xB1>(x);   // quad_perm xor 1
  x = dpp_add<0x4E>(x);   // quad_perm xor 2
  x = dpp_add<0x124>(x);  // row_ror:4
  x = dpp_add<0x128>(x);  // row_ror:8
  return x;
}

// ---------------------------------------------------------------------------
// Kernel 1: fused q/k/v projection.  proj[b][i] = dot(W_all[i], x[b])
// ---------------------------------------------------------------------------
#define PROJ_RPB 4
__global__ __launch_bounds__(256) void proj_kernel(
    const float* __restrict__ x, const float* __restrict__ Wq,
    const float* __restrict__ Wk, const float* __restrict__ Wv,
    float* __restrict__ proj) {
  int tid = threadIdx.x;
  int bb = tid & 15, kc = tid >> 4;
  int row0 = blockIdx.x * PROJ_RPB;
  const float* xp = x + (size_t)bb * EMBED + kc * 128;
  const float* wr[PROJ_RPB];
#pragma unroll
  for (int r = 0; r < PROJ_RPB; ++r) {
    int row = row0 + r;
    wr[r] = (row < 2048 ? Wq + (size_t)row * EMBED
             : row < 2560 ? Wk + (size_t)(row - 2048) * EMBED
                          : Wv + (size_t)(row - 2560) * EMBED) + kc * 128;
  }
  float a[PROJ_RPB] = {0.f, 0.f, 0.f, 0.f};
#pragma unroll
  for (int k = 0; k < 128; k += 8) {
    float4 x0 = *reinterpret_cast<const float4*>(xp + k);
    float4 x1 = *reinterpret_cast<const float4*>(xp + k + 4);
#pragma unroll
    for (int r = 0; r < PROJ_RPB; ++r) {
      float4 w0 = *reinterpret_cast<const float4*>(wr[r] + k);
      float4 w1 = *reinterpret_cast<const float4*>(wr[r] + k + 4);
      a[r] += dot4(w0, x0) + dot4(w1, x1);
    }
  }
  int w = tid >> 6, lane = tid & 63;
  __shared__ float red[4][PROJ_RPB][16];
#pragma unroll
  for (int r = 0; r < PROJ_RPB; ++r) {
    float s = a[r];
    s += __shfl_xor(s, 16);
    s += __shfl_xor(s, 32);
    if (lane < 16) red[w][r][lane] = s;
  }
  __syncthreads();
  if (tid < 16 * PROJ_RPB) {
    int r = tid >> 4, b2 = tid & 15;
    float v = red[0][r][b2] + red[1][r][b2] + red[2][r][b2] + red[3][r][b2];
    proj[(size_t)b2 * NQROWS + row0 + r] = v;
  }
}

// ---------------------------------------------------------------------------
// Kernel 2: flash-decode partials, one KV-cache block per workgroup.
// LDS double-buffered pipeline via global_load_lds DMA + counted vmcnt.
// Each wave stages and computes ONLY its own 8-token slice of each 32-token
// tile -> no cross-wave deps, no barriers in the main loop.
// ---------------------------------------------------------------------------
__global__ __launch_bounds__(256) void attn_partial_kernel(
    const float* __restrict__ blocks_k, const float* __restrict__ blocks_v,
    const float* __restrict__ proj, const int* __restrict__ last_offset,
    float* __restrict__ part_ms, float* __restrict__ part_o) {
  int nb = blockIdx.x, b = blockIdx.y, h = blockIdx.z;
  int tid = threadIdx.x;
  int w = tid >> 6, lane = tid & 63;
  int sub = lane >> 4, dl = (lane & 15) * 4;
  int myrow = w * 8;  // this wave's first token within a tile

  __shared__ __align__(16) float lds_k[2][TILE_T * HD];
  __shared__ __align__(16) float lds_v[2][TILE_T * HD];

  int valid = (nb == NBLK - 1) ? last_offset[0] : TB;

  // q fragments, pre-scaled by 1/sqrt(d) * log2(e)
  float4 qv[GQ];
  const float* qbase = proj + (size_t)b * NQROWS + h * GQ * HD + dl;
#pragma unroll
  for (int gi = 0; gi < GQ; ++gi) {
    float4 q = *reinterpret_cast<const float4*>(qbase + gi * HD);
    qv[gi] = make_float4(q.x * QSCALE, q.y * QSCALE, q.z * QSCALE, q.w * QSCALE);
  }
  // Drain q (and valid) loads so the compiler inserts no waits inside the loop.
  asm volatile("s_waitcnt vmcnt(0)" ::: "memory");

  size_t kvoff = (((size_t)nb * BATCH + b) * NKV + h) * (size_t)(TB * HD);
  const float* kg = blocks_k + kvoff;
  const float* vg = blocks_v + kvoff;

  float m[GQ], sm[GQ];
  float4 acc[GQ];
#pragma unroll
  for (int gi = 0; gi < GQ; ++gi) {
    m[gi] = -1e30f;
    sm[gi] = 0.f;
    acc[gi] = make_float4(0.f, 0.f, 0.f, 0.f);
  }

  // stage wave-own 8 tokens of tile `it` into buffer `buf` (4 x 1KB DMAs)
  auto STAGE = [&](int it, int buf) {
    int gbase = (it * TILE_T + myrow) * HD + lane * 4;  // per-lane float idx
#pragma unroll
    for (int i = 0; i < 2; ++i) {
      GLDS16(kg + gbase + i * 4 * HD, &lds_k[buf][(myrow + i * 4) * HD]);
      GLDS16(vg + gbase + i * 4 * HD, &lds_v[buf][(myrow + i * 4) * HD]);
    }
  };

  auto COMPUTE = [&](int it, int buf, bool masked) {
    float4 kf[2], vf[2];
#pragma unroll
    for (int grp = 0; grp < 2; ++grp) {
      kf[grp] = *reinterpret_cast<const float4*>(
          &lds_k[buf][(myrow + grp * 4 + sub) * HD + dl]);
      vf[grp] = *reinterpret_cast<const float4*>(
          &lds_v[buf][(myrow + grp * 4 + sub) * HD + dl]);
    }
    float s[2][GQ];
#pragma unroll
    for (int grp = 0; grp < 2; ++grp)
#pragma unroll
      for (int gi = 0; gi < GQ; ++gi) s[grp][gi] = dot4(qv[gi], kf[grp]);
#pragma unroll
    for (int grp = 0; grp < 2; ++grp)
#pragma unroll
      for (int gi = 0; gi < GQ; ++gi) s[grp][gi] = red16(s[grp][gi]);
    if (masked) {
      int tok0 = it * TILE_T + myrow + sub;
#pragma unroll
      for (int grp = 0; grp < 2; ++grp)
        if (tok0 + grp * 4 >= valid)
#pragma unroll
          for (int gi = 0; gi < GQ; ++gi) s[grp][gi] = -1e30f;
    }
#pragma unroll
    for (int gi = 0; gi < GQ; ++gi) {
      float bm = fmaxf(s[0][gi], s[1][gi]);
      float mn = fmaxf(m[gi], bm);
      float c = exp2f(m[gi] - mn);
      float p0 = exp2f(s[0][gi] - mn);
      float p1 = exp2f(s[1][gi] - mn);
      sm[gi] = sm[gi] * c + (p0 + p1);
      acc[gi].x = acc[gi].x * c + (p0 * vf[0].x + p1 * vf[1].x);
      acc[gi].y = acc[gi].y * c + (p0 * vf[0].y + p1 * vf[1].y);
      acc[gi].z = acc[gi].z * c + (p0 * vf[0].z + p1 * vf[1].z);
      acc[gi].w = acc[gi].w * c + (p0 * vf[0].w + p1 * vf[1].w);
      m[gi] = mn;
    }
  };

  STAGE(0, 0);
#pragma unroll
  for (int it = 0; it < NTILE; ++it) {
    if (it + 1 < NTILE) {
      STAGE(it + 1, (it + 1) & 1);
      // wait for tile `it` (the 4 DMAs for it+1 stay in flight)
      asm volatile("s_waitcnt vmcnt(4)" ::: "memory");
    } else {
      asm volatile("s_waitcnt vmcnt(0)" ::: "memory");
    }
    __builtin_amdgcn_sched_barrier(0);
    bool masked = (it * TILE_T + myrow + 8) > valid;
    COMPUTE(it, it & 1, masked);
  }

  // merge the 4 token sub-slots (lane bits 4,5)
#pragma unroll
  for (int mask = 16; mask <= 32; mask <<= 1) {
#pragma unroll
    for (int gi = 0; gi < GQ; ++gi) {
      float mo = __shfl_xor(m[gi], mask);
      float so = __shfl_xor(sm[gi], mask);
      float4 ao;
      ao.x = __shfl_xor(acc[gi].x, mask);
      ao.y = __shfl_xor(acc[gi].y, mask);
      ao.z = __shfl_xor(acc[gi].z, mask);
      ao.w = __shfl_xor(acc[gi].w, mask);
      float mn = fmaxf(m[gi], mo);
      float c1 = exp2f(m[gi] - mn);
      float c2 = exp2f(mo - mn);
      sm[gi] = sm[gi] * c1 + so * c2;
      acc[gi].x = acc[gi].x * c1 + ao.x * c2;
      acc[gi].y = acc[gi].y * c1 + ao.y * c2;
      acc[gi].z = acc[gi].z * c1 + ao.z * c2;
      acc[gi].w = acc[gi].w * c1 + ao.w * c2;
      m[gi] = mn;
    }
  }

  // cross-wave merge via LDS
  __shared__ float lds_o[4][GQ][HD];
  __shared__ float lds_m[4][GQ];
  __shared__ float lds_s[4][GQ];
  if (lane < 16) {
#pragma unroll
    for (int gi = 0; gi < GQ; ++gi)
      *reinterpret_cast<float4*>(&lds_o[w][gi][dl]) = acc[gi];
    if (lane == 0) {
#pragma unroll
      for (int gi = 0; gi < GQ; ++gi) {
        lds_m[w][gi] = m[gi];
        lds_s[w][gi] = sm[gi];
      }
    }
  }
  __syncthreads();

  if (w == 0) {
    int d = lane;  // 0..63
#pragma unroll
    for (int gi = 0; gi < GQ; ++gi) {
      float M = fmaxf(fmaxf(lds_m[0][gi], lds_m[1][gi]),
                      fmaxf(lds_m[2][gi], lds_m[3][gi]));
      float sum = 0.f, o = 0.f;
#pragma unroll
      for (int ww = 0; ww < 4; ++ww) {
        float c = exp2f(lds_m[ww][gi] - M);
        sum += lds_s[ww][gi] * c;
        o += lds_o[ww][gi][d] * c;
      }
      size_t idx = (((size_t)b * NKV + h) * GQ + gi) * NBLK + nb;
      if (lane == 0) {
        part_ms[idx * 2] = M;
        part_ms[idx * 2 + 1] = sum;
      }
      part_o[idx * HD + d] = o;
    }
  }
}

// ---------------------------------------------------------------------------
// Kernel 3: merge 16 block-partials + current token per (b,h,gi) (log2 domain).
// ---------------------------------------------------------------------------
__global__ __launch_bounds__(256) void reduce_kernel(
    const float* __restrict__ proj, const float* __restrict__ part_ms,
    const float* __restrict__ part_o, float* __restrict__ atten) {
  int tid = threadIdx.x;
  int wi = blockIdx.x * 4 + (tid >> 6);
  int lane = tid & 63;  // head-dim d
  int b = wi >> 5;
  int h = (wi >> 2) & 7;
  int gi = wi & 3;
  size_t pidx = (((size_t)b * NKV + h) * GQ + gi) * NBLK;

  float qd = proj[(size_t)b * NQROWS + (h * GQ + gi) * HD + lane];
  float kd = proj[(size_t)b * NQROWS + 2048 + h * HD + lane];
  float vd = proj[(size_t)b * NQROWS + 2560 + h * HD + lane];
  float sp = qd * kd;
#pragma unroll
  for (int mask = 1; mask < 64; mask <<= 1) sp += __shfl_xor(sp, mask);
  float s_cur = sp * QSCALE;  // log2 domain

  float pm[NBLK], ps[NBLK];
  float M = s_cur;
#pragma unroll
  for (int nb = 0; nb < NBLK; ++nb) {
    pm[nb] = part_ms[(pidx + nb) * 2];
    ps[nb] = part_ms[(pidx + nb) * 2 + 1];
    M = fmaxf(M, pm[nb]);
  }
  float p_cur = exp2f(s_cur - M);
  float sum = p_cur;
  float o = p_cur * vd;
#pragma unroll
  for (int nb = 0; nb < NBLK; ++nb) {
    float c = exp2f(pm[nb] - M);
    sum += ps[nb] * c;
    o += part_o[(pidx + nb) * HD + lane] * c;
  }
  atten[(size_t)b * EMBED + (h * GQ + gi) * HD + lane] = o / sum;
}

// ---------------------------------------------------------------------------
// Kernel 4: out[b][i] = dot(Wo[i], atten[b])
// ---------------------------------------------------------------------------
#define OUT_RPB 4
__global__ __launch_bounds__(256) void out_kernel(
    const float* __restrict__ atten, const float* __restrict__ Wo,
    float* __restrict__ out) {
  int tid = threadIdx.x;
  int bb = tid & 15, kc = tid >> 4;
  int row0 = blockIdx.x * OUT_RPB;
  const float* xp = atten + (size_t)bb * EMBED + kc * 128;
  float a[OUT_RPB] = {0.f, 0.f, 0.f, 0.f};
#pragma unroll
  for (int k = 0; k < 128; k += 8) {
    float4 x0 = *reinterpret_cast<const float4*>(xp + k);
    float4 x1 = *reinterpret_cast<const float4*>(xp + k + 4);
#pragma unroll
    for (int r = 0; r < OUT_RPB; ++r) {
      const float* wp = Wo + (size_t)(row0 + r) * EMBED + kc * 128;
      float4 w0 = *reinterpret_cast<const float4*>(wp + k);
      float4 w1 = *reinterpret_cast<const float4*>(wp + k + 4);
      a[r] += dot4(w0, x0) + dot4(w1, x1);
    }
  }
  int w = tid >> 6, lane = tid & 63;
  __shared__ float red[4][OUT_RPB][16];
#pragma unroll
  for (int r = 0; r < OUT_RPB; ++r) {
    float s = a[r];
    s += __shfl_xor(s, 16);
    s += __shfl_xor(s, 32);
    if (lane < 16) red[w][r][lane] = s;
  }
  __syncthreads();
  if (tid < 16 * OUT_RPB) {
    int r = tid >> 4, b2 = tid & 15;
    float v = red[0][r][b2] + red[1][r][b2] + red[2][r][b2] + red[3][r][b2];
    out[(size_t)b2 * EMBED + row0 + r] = v;
  }
}

// ---------------------------------------------------------------------------
extern "C" void kernel_launch(void* const* d_in, const int* in_sizes, int n_in,
                              void* d_out, int out_size, void* d_ws, size_t ws_size,
                              hipStream_t stream) {
  const float* x = (const float*)d_in[0];
  const float* bk = (const float*)d_in[1];
  const float* bv = (const float*)d_in[2];
  const float* Wq = (const float*)d_in[3];
  const float* Wk = (const float*)d_in[4];
  const float* Wv = (const float*)d_in[5];
  const float* Wo = (const float*)d_in[6];
  const int* lo = (const int*)d_in[7];

  float* ws = (float*)d_ws;
  float* proj = ws;
  float* part_ms = ws + OFF_PARTMS;
  float* part_o = ws + OFF_PARTO;
  float* atten = ws + OFF_ATTEN;
  float* out = (float*)d_out;

  proj_kernel<<<NQROWS / PROJ_RPB, 256, 0, stream>>>(x, Wq, Wk, Wv, proj);
  attn_partial_kernel<<<dim3(NBLK, BATCH, NKV), 256, 0, stream>>>(
      bk, bv, proj, lo, part_ms, part_o);
  reduce_kernel<<<(BATCH * NKV * GQ) / 4, 256, 0, stream>>>(
      proj, part_ms, part_o, atten);
  out_kernel<<<EMBED / OUT_RPB, 256, 0, stream>>>(atten, Wo, out);
}